// Round 4
// baseline (115.886 us; speedup 1.0000x reference)
//
#include <hip/hip_runtime.h>

// N_RNA=20000, N_PROT=5000, D=128, C=4, E=500000
#define DIM 128
#define NCLS 4

typedef _Float16 f16x8 __attribute__((ext_vector_type(8)));
typedef float    f32x4 __attribute__((ext_vector_type(4)));

// ---------- fp32 -> fp16 conversion into workspace ----------
__global__ __launch_bounds__(256) void cvt_f16_kernel(
    const float* __restrict__ src, _Float16* __restrict__ dst, int n)
{
    // 8 floats -> 8 halves (16B store) per thread per step
    int i = (blockIdx.x * blockDim.x + threadIdx.x) * 8;
    const int stride = gridDim.x * blockDim.x * 8;
    for (; i + 7 < n; i += stride) {
        const float4 a = *(const float4*)(src + i);
        const float4 b = *(const float4*)(src + i + 4);
        f16x8 o;
        o[0] = (_Float16)a.x; o[1] = (_Float16)a.y;
        o[2] = (_Float16)a.z; o[3] = (_Float16)a.w;
        o[4] = (_Float16)b.x; o[5] = (_Float16)b.y;
        o[6] = (_Float16)b.z; o[7] = (_Float16)b.w;
        *(f16x8*)(dst + i) = o;
    }
}

// ---------- MFMA decoder ----------
// One wave handles 16 edges per task. A-frag: q[m=lane&15][k=quad*8+j] (f16),
// B-frag: wf[n=lane&15][k=quad*8+j] (classes n>=4 zeroed). D[row=quad*4+reg][col=lane&15].
__global__ __launch_bounds__(256) void decoder_mfma_kernel(
    const _Float16* __restrict__ rna,   // [N_RNA, D] f16
    const _Float16* __restrict__ prot,  // [N_PROT, D] f16
    const int*   __restrict__ ridx,
    const int*   __restrict__ pidx,
    const float* __restrict__ wrel,     // [C, D] f32
    const float* __restrict__ wcls,     // [C, C] f32
    float*       __restrict__ out,      // [E, C]
    int nEdges)
{
    const int lane   = threadIdx.x & 63;
    const int m      = lane & 15;       // edge-within-task row / class col
    const int quad   = lane >> 4;
    const int wave   = (blockIdx.x * blockDim.x + threadIdx.x) >> 6;
    const int nwaves = (gridDim.x * blockDim.x) >> 6;

    // Build B fragments: wf_n[d] = sum_c wrel[c,d] * wcls[c,n], n = lane&15.
    // One fragment per K-tile (d0 = t*32 + quad*8).
    const float wc0 = (m < NCLS) ? wcls[0 * NCLS + m] : 0.0f;
    const float wc1 = (m < NCLS) ? wcls[1 * NCLS + m] : 0.0f;
    const float wc2 = (m < NCLS) ? wcls[2 * NCLS + m] : 0.0f;
    const float wc3 = (m < NCLS) ? wcls[3 * NCLS + m] : 0.0f;
    f16x8 bfrag[4];
#pragma unroll
    for (int t = 0; t < 4; ++t) {
        const int d0 = t * 32 + quad * 8;
        const float4 r0a = *(const float4*)(wrel + 0 * DIM + d0);
        const float4 r0b = *(const float4*)(wrel + 0 * DIM + d0 + 4);
        const float4 r1a = *(const float4*)(wrel + 1 * DIM + d0);
        const float4 r1b = *(const float4*)(wrel + 1 * DIM + d0 + 4);
        const float4 r2a = *(const float4*)(wrel + 2 * DIM + d0);
        const float4 r2b = *(const float4*)(wrel + 2 * DIM + d0 + 4);
        const float4 r3a = *(const float4*)(wrel + 3 * DIM + d0);
        const float4 r3b = *(const float4*)(wrel + 3 * DIM + d0 + 4);
        bfrag[t][0] = (_Float16)(wc0 * r0a.x + wc1 * r1a.x + wc2 * r2a.x + wc3 * r3a.x);
        bfrag[t][1] = (_Float16)(wc0 * r0a.y + wc1 * r1a.y + wc2 * r2a.y + wc3 * r3a.y);
        bfrag[t][2] = (_Float16)(wc0 * r0a.z + wc1 * r1a.z + wc2 * r2a.z + wc3 * r3a.z);
        bfrag[t][3] = (_Float16)(wc0 * r0a.w + wc1 * r1a.w + wc2 * r2a.w + wc3 * r3a.w);
        bfrag[t][4] = (_Float16)(wc0 * r0b.x + wc1 * r1b.x + wc2 * r2b.x + wc3 * r3b.x);
        bfrag[t][5] = (_Float16)(wc0 * r0b.y + wc1 * r1b.y + wc2 * r2b.y + wc3 * r3b.y);
        bfrag[t][6] = (_Float16)(wc0 * r0b.z + wc1 * r1b.z + wc2 * r2b.z + wc3 * r3b.z);
        bfrag[t][7] = (_Float16)(wc0 * r0b.w + wc1 * r1b.w + wc2 * r2b.w + wc3 * r3b.w);
    }

    const int nTasks = (nEdges + 15) >> 4;

    for (int task = wave; task < nTasks; task += nwaves) {
        const int e0 = task << 4;
        // Per-lane edge index (clamped for tail safety; E=500000 has no tail)
        const int e  = e0 + m;
        const int ec = (e < nEdges) ? e : (nEdges - 1);
        const int ri = ridx[ec];
        const int pi = pidx[ec];
        const _Float16* rrow = rna  + (size_t)ri * DIM + quad * 8;
        const _Float16* prow = prot + (size_t)pi * DIM + quad * 8;

        f32x4 acc = {0.f, 0.f, 0.f, 0.f};
#pragma unroll
        for (int t = 0; t < 4; ++t) {
            const f16x8 rv = *(const f16x8*)(rrow + t * 32);
            const f16x8 pv = *(const f16x8*)(prow + t * 32);
            const f16x8 q  = rv * pv;   // v_pk_mul_f16 x4
            acc = __builtin_amdgcn_mfma_f32_16x16x32_f16(q, bfrag[t], acc, 0, 0, 0);
        }

        // D[row=quad*4+reg][col=m] ; col = class, row = edge offset
        if (m < NCLS) {
#pragma unroll
            for (int reg = 0; reg < 4; ++reg) {
                const int ee = e0 + quad * 4 + reg;
                if (ee < nEdges)
                    out[(size_t)ee * NCLS + m] = fmaxf(acc[reg], 0.0f);
            }
        }
    }
}

// ---------- fp32 fallback (R2 kernel) if workspace is too small ----------
__device__ __forceinline__ float reduce4(float b0, float b1, float b2, float b3, int lane)
{
    const bool lo1 = (lane & 1) == 0;
    float k0 = lo1 ? b0 : b2, s0 = lo1 ? b2 : b0;
    float k1 = lo1 ? b1 : b3, s1 = lo1 ? b3 : b1;
    float v0 = k0 + __shfl_xor(s0, 1, 32);
    float v1 = k1 + __shfl_xor(s1, 1, 32);
    const bool lo2 = (lane & 2) == 0;
    float k = lo2 ? v0 : v1, s = lo2 ? v1 : v0;
    float v = k + __shfl_xor(s, 2, 32);
    v += __shfl_xor(v, 4, 32);
    v += __shfl_xor(v, 8, 32);
    v += __shfl_xor(v, 16, 32);
    return v;
}

__global__ __launch_bounds__(256) void decoder_f32_kernel(
    const float* __restrict__ rna, const float* __restrict__ prot,
    const int* __restrict__ ridx, const int* __restrict__ pidx,
    const float* __restrict__ wrel, const float* __restrict__ wcls,
    float* __restrict__ out, int nEdges)
{
    const int lane32 = threadIdx.x & 31;
    const int hw     = (blockIdx.x * blockDim.x + threadIdx.x) >> 5;
    const int nhw    = (gridDim.x * blockDim.x) >> 5;
    const float4 w0 = *(const float4*)(wrel + 0 * DIM + lane32 * 4);
    const float4 w1 = *(const float4*)(wrel + 1 * DIM + lane32 * 4);
    const float4 w2 = *(const float4*)(wrel + 2 * DIM + lane32 * 4);
    const float4 w3 = *(const float4*)(wrel + 3 * DIM + lane32 * 4);
    float wc[16];
#pragma unroll
    for (int i = 0; i < 16; ++i) wc[i] = wcls[i];
    float4 wf[4];
#pragma unroll
    for (int j = 0; j < 4; ++j) {
        wf[j].x = wc[j] * w0.x + wc[4 + j] * w1.x + wc[8 + j] * w2.x + wc[12 + j] * w3.x;
        wf[j].y = wc[j] * w0.y + wc[4 + j] * w1.y + wc[8 + j] * w2.y + wc[12 + j] * w3.y;
        wf[j].z = wc[j] * w0.z + wc[4 + j] * w1.z + wc[8 + j] * w2.z + wc[12 + j] * w3.z;
        wf[j].w = wc[j] * w0.w + wc[4 + j] * w1.w + wc[8 + j] * w2.w + wc[12 + j] * w3.w;
    }
    const int cls   = ((lane32 & 1) << 1) | ((lane32 >> 1) & 1);
    const int lelem = lane32 * 4;
    for (int e = hw; e < nEdges; e += nhw) {
        const float4 r = *(const float4*)(rna  + (size_t)ridx[e] * DIM + lelem);
        const float4 p = *(const float4*)(prot + (size_t)pidx[e] * DIM + lelem);
        float qx = r.x * p.x, qy = r.y * p.y, qz = r.z * p.z, qw = r.w * p.w;
        float b0 = qx * wf[0].x + qy * wf[0].y + qz * wf[0].z + qw * wf[0].w;
        float b1 = qx * wf[1].x + qy * wf[1].y + qz * wf[1].z + qw * wf[1].w;
        float b2 = qx * wf[2].x + qy * wf[2].y + qz * wf[2].z + qw * wf[2].w;
        float b3 = qx * wf[3].x + qy * wf[3].y + qz * wf[3].z + qw * wf[3].w;
        const float v = reduce4(b0, b1, b2, b3, lane32);
        if (lane32 < 4) out[(size_t)e * NCLS + cls] = fmaxf(v, 0.0f);
    }
}

extern "C" void kernel_launch(void* const* d_in, const int* in_sizes, int n_in,
                              void* d_out, int out_size, void* d_ws, size_t ws_size,
                              hipStream_t stream) {
    const float* rna  = (const float*)d_in[0];
    const float* prot = (const float*)d_in[1];
    const int*   ridx = (const int*)d_in[2];
    const int*   pidx = (const int*)d_in[3];
    const float* wrel = (const float*)d_in[4];
    const float* wcls = (const float*)d_in[5];
    float*       out  = (float*)d_out;

    const int nRnaElems  = in_sizes[0];   // 20000*128
    const int nProtElems = in_sizes[1];   // 5000*128
    const int nEdges     = in_sizes[2];   // 500000

    const size_t rnaBytes  = (size_t)nRnaElems * 2;
    const size_t needBytes = rnaBytes + (size_t)nProtElems * 2;

    if (ws_size >= needBytes) {
        _Float16* rnaH  = (_Float16*)d_ws;
        _Float16* protH = (_Float16*)((char*)d_ws + rnaBytes);

        {
            const int blocksR = (nRnaElems / 8 + 255) / 256;
            hipLaunchKernelGGL(cvt_f16_kernel, dim3(blocksR), dim3(256), 0, stream,
                               rna, rnaH, nRnaElems);
            const int blocksP = (nProtElems / 8 + 255) / 256;
            hipLaunchKernelGGL(cvt_f16_kernel, dim3(blocksP), dim3(256), 0, stream,
                               prot, protH, nProtElems);
        }

        // 2048 blocks x 256 = 8192 waves, ~3.8 tasks of 16 edges each.
        hipLaunchKernelGGL(decoder_mfma_kernel, dim3(2048), dim3(256), 0, stream,
                           rnaH, protH, ridx, pidx, wrel, wcls, out, nEdges);
    } else {
        hipLaunchKernelGGL(decoder_f32_kernel, dim3(8192), dim3(256), 0, stream,
                           rna, prot, ridx, pidx, wrel, wcls, out, nEdges);
    }
}